// Round 2
// baseline (539.756 us; speedup 1.0000x reference)
//
#include <hip/hip_runtime.h>

#define NB 4096
#define NT 512

// sigmoid via native v_exp_f32 + v_rcp_f32 (safe at +-inf: no NaN)
__device__ __forceinline__ float fsig(float x) {
    return __builtin_amdgcn_rcpf(1.0f + __expf(-x));
}
__device__ __forceinline__ float ftanh(float x) {
    return 2.0f * __builtin_amdgcn_rcpf(1.0f + __expf(-2.0f * x)) - 1.0f;
}

// One wave (64 lanes) per batch element. Lane (half,k) owns gate rows
// half*32+k and 64+half*32+k  (half0: i,g ; half1: f,o) -> 64 W_hh floats in
// VGPRs. h broadcast through a 64-float LDS slot; halves exchange activations
// with __shfl_xor(.,32); both halves redundantly compute c/h (bitwise equal,
// no divergence). Workgroup = 1 wave, so __syncthreads() lowers to waitcnt
// only (no s_barrier). x is staged to LDS once -> zero VMEM in steady loop.
__global__ __launch_bounds__(64, 4) void lstm_fused_kernel(
    const float* __restrict__ x,
    const float* __restrict__ W_ih,
    const float* __restrict__ W_hh,
    const float* __restrict__ b_ih,
    const float* __restrict__ b_hh,
    const float* __restrict__ W1,
    const float* __restrict__ b1,
    const float* __restrict__ W2,
    const float* __restrict__ b2,
    float* __restrict__ out)
{
    const int lane = threadIdx.x;
    const int k    = lane & 31;
    const int half = lane >> 5;   // 0: rows [k, 64+k] = i,g ; 1: [32+k, 96+k] = f,o
    const int batch = blockIdx.x;

    __shared__ float sh_x[NT * 2];   // this batch's x, staged once (4 KB)
    __shared__ float sh_ht[64];      // [0..31] = h, [32..63] = tanh(h)

    // ---- stage x[batch] into LDS (256 float4 loads, coalesced) ----
    {
        const float4* xs = (const float4*)(x + (long)batch * (NT * 2));
        float4* xd = (float4*)sh_x;
#pragma unroll
        for (int i = 0; i < 4; ++i) xd[lane + 64 * i] = xs[lane + 64 * i];
    }

    // ---- preload weights into registers ----
    const int row0 = half * 32 + k;        // i (half0) / f (half1)
    const int row1 = 64 + half * 32 + k;   // g (half0) / o (half1)
    float Wr0[32], Wr1[32];
    const float4* W4 = (const float4*)W_hh;
#pragma unroll
    for (int q = 0; q < 8; ++q) {
        float4 w = W4[row0 * 8 + q];
        Wr0[4*q+0] = w.x; Wr0[4*q+1] = w.y; Wr0[4*q+2] = w.z; Wr0[4*q+3] = w.w;
        w = W4[row1 * 8 + q];
        Wr1[4*q+0] = w.x; Wr1[4*q+1] = w.y; Wr1[4*q+2] = w.z; Wr1[4*q+3] = w.w;
    }
    const float wi00 = W_ih[row0 * 2 + 0], wi01 = W_ih[row0 * 2 + 1];
    const float wi10 = W_ih[row1 * 2 + 0], wi11 = W_ih[row1 * 2 + 1];
    const float bias0 = b_ih[row0] + b_hh[row0];
    const float bias1 = b_ih[row1] + b_hh[row1];

    // head: 4 lanes per fc1 output d, each covering 8 of the 32 inputs
    const int d   = lane & 15;
    const int seg = lane >> 4;
    float W1r[8];
    {
        const float4* W14 = (const float4*)(W1 + d * 32 + seg * 8);
        const float4 wa = W14[0], wb = W14[1];
        W1r[0]=wa.x; W1r[1]=wa.y; W1r[2]=wa.z; W1r[3]=wa.w;
        W1r[4]=wb.x; W1r[5]=wb.y; W1r[6]=wb.z; W1r[7]=wb.w;
    }
    const float b1r = (seg == 0) ? b1[d] : 0.0f;
    const float w2r = W2[d];
    const float b2v = b2[0];

    sh_ht[lane] = 0.0f;   // h = 0, tanh(h) = 0
    __syncthreads();      // single-wave workgroup: lowers to waitcnt

    float c = 0.0f;
    float* outp = out + (long)batch * NT;
    const float4* hp = (const float4*)sh_ht;          // h broadcast
    const float2* x2 = (const float2*)sh_x;
    const float4* tp = (const float4*)(sh_ht + 32 + seg * 8);  // th segment

    for (int t = 0; t < NT; ++t) {
        const float2 xv = x2[t];   // broadcast LDS read

        // ---- 2 gate rows x 32 FMAs, h broadcast from LDS ----
        float a0 = fmaf(xv.x, wi00, fmaf(xv.y, wi01, bias0));
        float a1 = fmaf(xv.x, wi10, fmaf(xv.y, wi11, bias1));
#pragma unroll
        for (int q = 0; q < 8; ++q) {
            const float4 hv = hp[q];
            a0 = fmaf(Wr0[4*q+0], hv.x, a0);
            a1 = fmaf(Wr1[4*q+0], hv.x, a1);
            a0 = fmaf(Wr0[4*q+1], hv.y, a0);
            a1 = fmaf(Wr1[4*q+1], hv.y, a1);
            a0 = fmaf(Wr0[4*q+2], hv.z, a0);
            a1 = fmaf(Wr1[4*q+2], hv.z, a1);
            a0 = fmaf(Wr0[4*q+3], hv.w, a0);
            a1 = fmaf(Wr1[4*q+3], hv.w, a1);
        }

        // ---- activations: act0 = sigmoid(a0) always;
        //      act1 = tanh(a1) on half0, sigmoid(a1) on half1 (branchless) ----
        const float act0 = fsig(a0);
        const float s1 = __builtin_amdgcn_rcpf(
            1.0f + __expf(half ? -a1 : -2.0f * a1));
        const float act1 = half ? s1 : fmaf(2.0f, s1, -1.0f);

        // exchange with partner half
        const float sw0 = __shfl_xor(act0, 32);
        const float sw1 = __shfl_xor(act1, 32);
        const float ig = half ? sw0 : act0;
        const float fg = half ? act0 : sw0;
        const float gg = half ? sw1 : act1;
        const float og = half ? act1 : sw1;

        c = fmaf(fg, c, ig * gg);
        const float hk  = og * ftanh(c);
        const float thk = ftanh(hk);          // lstm_out = tanh(h)

        sh_ht[lane] = half ? thk : hk;        // [0..31]=h, [32..63]=th
        __syncthreads();                      // waitcnt only (1-wave group)

        // ---- head: fc1 partials (4 lanes per output) + fc2 reduce ----
        float f1 = b1r;
        {
            const float4 t0 = tp[0], t1 = tp[1];
            f1 = fmaf(W1r[0], t0.x, f1);
            f1 = fmaf(W1r[1], t0.y, f1);
            f1 = fmaf(W1r[2], t0.z, f1);
            f1 = fmaf(W1r[3], t0.w, f1);
            f1 = fmaf(W1r[4], t1.x, f1);
            f1 = fmaf(W1r[5], t1.y, f1);
            f1 = fmaf(W1r[6], t1.z, f1);
            f1 = fmaf(W1r[7], t1.w, f1);
        }
        f1 += __shfl_xor(f1, 16);             // combine 4 segs
        f1 += __shfl_xor(f1, 32);
        float p = ftanh(f1) * w2r;
        p += __shfl_xor(p, 8);                // sum 16 outputs
        p += __shfl_xor(p, 4);
        p += __shfl_xor(p, 2);
        p += __shfl_xor(p, 1);
        if (lane == 0) outp[t] = p + b2v;
    }
}

extern "C" void kernel_launch(void* const* d_in, const int* in_sizes, int n_in,
                              void* d_out, int out_size, void* d_ws, size_t ws_size,
                              hipStream_t stream) {
    const float* x    = (const float*)d_in[0];
    const float* W_ih = (const float*)d_in[1];
    const float* W_hh = (const float*)d_in[2];
    const float* b_ih = (const float*)d_in[3];
    const float* b_hh = (const float*)d_in[4];
    const float* W1   = (const float*)d_in[5];
    const float* b1   = (const float*)d_in[6];
    const float* W2   = (const float*)d_in[7];
    const float* b2   = (const float*)d_in[8];
    float* out = (float*)d_out;

    lstm_fused_kernel<<<dim3(NB), dim3(64), 0, stream>>>(
        x, W_ih, W_hh, b_ih, b_hh, W1, b1, W2, b2, out);
}

// Round 4
// 348.880 us; speedup vs baseline: 1.5471x; 1.5471x over previous
//
#include <hip/hip_runtime.h>

#define NB 4096
#define NT 512
#define HSTRIDE 40   // ushort stride per batch row (80 B, 16B-aligned, low-conflict)

typedef float f32x4 __attribute__((ext_vector_type(4)));
typedef short bf16x8 __attribute__((ext_vector_type(8)));

__device__ __forceinline__ float fsig(float x) {
    return __builtin_amdgcn_rcpf(1.0f + __expf(-x));
}
__device__ __forceinline__ float ftanh(float x) {
    return 2.0f * __builtin_amdgcn_rcpf(1.0f + __expf(-2.0f * x)) - 1.0f;
}
// f32 -> bf16 round-to-nearest-even (NaN irrelevant here)
__device__ __forceinline__ unsigned short f2bf(float f) {
    unsigned u = __builtin_bit_cast(unsigned, f);
    u += 0x7fffu + ((u >> 16) & 1u);
    return (unsigned short)(u >> 16);
}
__device__ __forceinline__ float bf2f(unsigned short h) {
    return __builtin_bit_cast(float, (unsigned)h << 16);
}
// x += row_shr<N>(x), bound_ctrl: OOB lanes contribute 0 (suffix-scan reduce)
template <int CTRL>
__device__ __forceinline__ float dpp_add(float x) {
    int s = __builtin_amdgcn_update_dpp(
        0, __builtin_bit_cast(int, x), CTRL, 0xF, 0xF, true);
    return x + __builtin_bit_cast(float, s);
}

// 256 blocks x 8 waves x 16 batches. Per step, wave w does ONE
// mfma_f32_16x16x32_bf16: A = permuted W_hh tile (rows m -> gate (m&3),
// hidden 4w+(m>>2)), B = h[t-1] for 16 batches (split bf16 hi+lo -> 2 MFMAs
// for near-fp32 accuracy). C/D layout (col=lane&15, row=(lane>>4)*4+reg)
// then gives lane (g=lane>>4, n=lane&15) all 4 gates of hidden j=4w+g for
// batch n -> activations fully in-register, one barrier per step.
__global__ __launch_bounds__(512, 2) void lstm_mfma_kernel(
    const float* __restrict__ x,
    const float* __restrict__ W_ih,
    const float* __restrict__ W_hh,
    const float* __restrict__ b_ih,
    const float* __restrict__ b_hh,
    const float* __restrict__ W1,
    const float* __restrict__ b1,
    const float* __restrict__ W2,
    const float* __restrict__ b2,
    float* __restrict__ out)
{
    const int tid  = threadIdx.x;
    const int wid  = tid >> 6;
    const int lane = tid & 63;
    const int g    = lane >> 4;     // k-group / C row-group
    const int n    = lane & 15;     // batch column
    const int j    = 4 * wid + g;   // hidden unit owned by this lane
    const int batch0 = blockIdx.x * 16;

    __shared__ __align__(16) unsigned short sh_h[2][2][16][HSTRIDE]; // [buf][hi/lo]
    __shared__ __align__(16) unsigned short sh_t[2][16][HSTRIDE];    // tanh(h) bf16

    // ---- A fragment: lane holds row m=lane&15, k = 8g..8g+7 ----
    bf16x8 afrag;
    {
        const int m = lane & 15;
        const int grow = (m & 3) * 32 + 4 * wid + (m >> 2);
        const float* wp = W_hh + grow * 32 + 8 * g;
#pragma unroll
        for (int i = 0; i < 8; ++i) afrag[i] = (short)f2bf(wp[i]);
    }

    // ---- per-lane gate params for hidden j: rows r*32+j ----
    float wih0[4], wih1[4], bias[4];
#pragma unroll
    for (int r = 0; r < 4; ++r) {
        const int row = r * 32 + j;
        wih0[r] = W_ih[row * 2 + 0];
        wih1[r] = W_ih[row * 2 + 1];
        bias[r] = b_ih[row] + b_hh[row];
    }

    // ---- head setup: batch n0, fc1 output d, input half s ----
    const int n0 = 2 * wid + (lane >> 5);
    const int d  = lane & 15;
    const int s  = (lane >> 4) & 1;
    float w1r[16];
    {
        const float* wp = W1 + d * 32 + s * 16;
#pragma unroll
        for (int i = 0; i < 16; ++i) w1r[i] = wp[i];
    }
    const float b1r = (s == 0) ? b1[d] : 0.0f;
    const float w2r = W2[d];
    const float b2v = b2[0];

    // ---- zero-init LDS state (h0 = 0) ----
    {
        unsigned short* ph = (unsigned short*)sh_h;
        unsigned short* pt = (unsigned short*)sh_t;
        for (int i = tid; i < 2 * 2 * 16 * HSTRIDE; i += 512) {
            ph[i] = 0;
            if (i < 2 * 16 * HSTRIDE) pt[i] = 0;
        }
    }
    __syncthreads();

    const float2* xp = (const float2*)x + (size_t)(batch0 + n) * NT;
    float2 xv = xp[0];
    float c = 0.0f;
    float* outp = out + (size_t)(batch0 + n0) * NT;

    int cur = 0;
    for (int t = 0; t < NT; ++t) {
        // C init = biases + W_ih * x_t  (fp32)
        f32x4 acc;
#pragma unroll
        for (int r = 0; r < 4; ++r)
            acc[r] = fmaf(xv.x, wih0[r], fmaf(xv.y, wih1[r], bias[r]));

        // gates += W_hh * (h_hi + h_lo)
        const bf16x8 bhi = *(const bf16x8*)&sh_h[cur][0][n][8 * g];
        const bf16x8 blo = *(const bf16x8*)&sh_h[cur][1][n][8 * g];
        acc = __builtin_amdgcn_mfma_f32_16x16x32_bf16(afrag, bhi, acc, 0, 0, 0);
        acc = __builtin_amdgcn_mfma_f32_16x16x32_bf16(afrag, blo, acc, 0, 0, 0);

        const float2 xn = xp[(t + 1 < NT) ? t + 1 : t];   // prefetch

        // ---- activations (lane owns batch n, hidden j; c stays in reg) ----
        const float ig = fsig(acc[0]);
        const float fg = fsig(acc[1]);
        const float gg = ftanh(acc[2]);
        const float og = fsig(acc[3]);
        c = fmaf(fg, c, ig * gg);
        const float hk  = og * ftanh(c);
        const float thk = ftanh(hk);

        const int nxt = cur ^ 1;
        const unsigned short hhi = f2bf(hk);
        sh_h[nxt][0][n][j] = hhi;
        sh_h[nxt][1][n][j] = f2bf(hk - bf2f(hhi));  // residual -> ~fp32 h
        sh_t[nxt][n][j]    = f2bf(thk);
        __syncthreads();   // the one barrier: h/th(t) visible to all waves

        // ---- head for batch n0: fc1(d over half s) + tanh + fc2 ----
        const uint4* tq = (const uint4*)&sh_t[nxt][n0][16 * s];
        const uint4 ta = tq[0], tb = tq[1];
        float f1 = b1r;
#define HFMA(u, i0) \
        f1 = fmaf(__builtin_bit_cast(float, (unsigned)(u) << 16), w1r[i0], f1); \
        f1 = fmaf(__builtin_bit_cast(float, (unsigned)(u) & 0xffff0000u), w1r[(i0) + 1], f1);
        HFMA(ta.x, 0)  HFMA(ta.y, 2)  HFMA(ta.z, 4)  HFMA(ta.w, 6)
        HFMA(tb.x, 8)  HFMA(tb.y, 10) HFMA(tb.z, 12) HFMA(tb.w, 14)
#undef HFMA
        f1 += __shfl_xor(f1, 16);          // fold the two halves s=0/1
        float p = ftanh(f1) * w2r;
        p = dpp_add<0x118>(p);             // row_shr:8
        p = dpp_add<0x114>(p);             // row_shr:4
        p = dpp_add<0x112>(p);             // row_shr:2
        p = dpp_add<0x111>(p);             // row_shr:1 -> lane15 of each row = sum
        if ((lane & 31) == 15) outp[t] = p + b2v;

        xv = xn;
        cur = nxt;
    }
}

extern "C" void kernel_launch(void* const* d_in, const int* in_sizes, int n_in,
                              void* d_out, int out_size, void* d_ws, size_t ws_size,
                              hipStream_t stream) {
    const float* x    = (const float*)d_in[0];
    const float* W_ih = (const float*)d_in[1];
    const float* W_hh = (const float*)d_in[2];
    const float* b_ih = (const float*)d_in[3];
    const float* b_hh = (const float*)d_in[4];
    const float* W1   = (const float*)d_in[5];
    const float* b1   = (const float*)d_in[6];
    const float* W2   = (const float*)d_in[7];
    const float* b2   = (const float*)d_in[8];
    float* out = (float*)d_out;

    lstm_mfma_kernel<<<dim3(NB / 16), dim3(512), 0, stream>>>(
        x, W_ih, W_hh, b_ih, b_hh, W1, b1, W2, b2, out);
}

// Round 5
// 219.426 us; speedup vs baseline: 2.4598x; 1.5900x over previous
//
#include <hip/hip_runtime.h>

#define NB 4096
#define NT 512
#define HS 40   // ushort stride per batch row (80 B: 16B-aligned, 2-way banks = free)

typedef float f32x4 __attribute__((ext_vector_type(4)));
typedef short bf16x8 __attribute__((ext_vector_type(8)));

__device__ __forceinline__ float fsig(float x) {
    return __builtin_amdgcn_rcpf(1.0f + __expf(-x));
}
__device__ __forceinline__ float ftanh(float x) {
    return 2.0f * __builtin_amdgcn_rcpf(1.0f + __expf(-2.0f * x)) - 1.0f;
}
// one inst packs two f32->bf16: result = [bf16(a) | bf16(b)<<16]
__device__ __forceinline__ unsigned cvt_pk_bf16(float a, float b) {
    unsigned r;
    asm("v_cvt_pk_bf16_f32 %0, %1, %2" : "=v"(r) : "v"(a), "v"(b));
    return r;
}
// RTNE f32->bf16 (prologue / weight prep only)
__device__ __forceinline__ unsigned short f2bf(float f) {
    unsigned u = __builtin_bit_cast(unsigned, f);
    u += 0x7fffu + ((u >> 16) & 1u);
    return (unsigned short)(u >> 16);
}
__device__ __forceinline__ float bf2f(unsigned short h) {
    return __builtin_bit_cast(float, (unsigned)h << 16);
}

// 256 blocks x 8 waves x 16 batches. Per step, wave w does the gate tile via
// mfma_f32_16x16x32_bf16 (A = permuted W_hh, B = h split bf16 hi+lo -> 2 MFMAs,
// near-fp32). C/D layout (col=lane&15=batch n, row=(lane>>4)*4+reg=gate) puts
// all 4 gates of hidden j=4*wid+g in one lane -> activations in-register, one
// barrier/step. th(bf16) staged in a double-buffered 8-step LDS chunk; every
// 8th step wave w computes the whole head for time-slice w with one MFMA pair
// (A = split-bf16 W1, C-init = b1) + 4 tanh + shfl reduce -> head cost ~8
// VALU/wave-step amortized instead of ~80.
__global__ __launch_bounds__(512, 2) void lstm_mfma_kernel(
    const float* __restrict__ x,
    const float* __restrict__ W_ih,
    const float* __restrict__ W_hh,
    const float* __restrict__ b_ih,
    const float* __restrict__ b_hh,
    const float* __restrict__ W1,
    const float* __restrict__ b1,
    const float* __restrict__ W2,
    const float* __restrict__ b2,
    float* __restrict__ out)
{
    const int tid  = threadIdx.x;
    const int wid  = tid >> 6;
    const int lane = tid & 63;
    const int g    = lane >> 4;     // row-group (C rows 4g..4g+3)
    const int n    = lane & 15;     // batch column
    const int j    = 4 * wid + g;   // hidden unit owned by this lane
    const int batch0 = blockIdx.x * 16;

    __shared__ __align__(16) unsigned short sh_h[2][2][16][HS]; // [buf][hi/lo][n][j]
    __shared__ __align__(16) unsigned short sh_t[2][8][16][HS]; // [buf][tc][n][j] tanh(h)

    // ---- gate A fragment: lane holds row m=lane&15, k = 8g..8g+7 of the
    //      permuted W_hh tile (row m -> gate (m&3), hidden 4*wid+(m>>2)) ----
    bf16x8 afrag;
    {
        const int m = lane & 15;
        const int grow = (m & 3) * 32 + 4 * wid + (m >> 2);
        const float* wp = W_hh + grow * 32 + 8 * g;
#pragma unroll
        for (int i = 0; i < 8; ++i) afrag[i] = (short)f2bf(wp[i]);
    }

    // ---- per-lane gate params for hidden j: rows r*32+j ----
    float wihx[4], wihy[4], bias[4];
#pragma unroll
    for (int r = 0; r < 4; ++r) {
        const int row = r * 32 + j;
        wihx[r] = W_ih[row * 2 + 0];
        wihy[r] = W_ih[row * 2 + 1];
        bias[r] = b_ih[row] + b_hh[row];
    }

    // ---- head A fragment: W1 rows m=lane&15, split bf16 hi+lo ----
    bf16x8 w1hi, w1lo;
    {
        const float* wp = W1 + (lane & 15) * 32 + 8 * g;
#pragma unroll
        for (int i = 0; i < 8; ++i) {
            const float w = wp[i];
            const unsigned short hi = f2bf(w);
            w1hi[i] = (short)hi;
            w1lo[i] = (short)f2bf(w - bf2f(hi));
        }
    }
    float b1r[4], w2r[4];   // fc1 output d = 4g+r
#pragma unroll
    for (int r = 0; r < 4; ++r) {
        b1r[r] = b1[4 * g + r];
        w2r[r] = W2[4 * g + r];
    }
    const float b2v = b2[0];

    // ---- zero-init h state ----
    {
        unsigned short* ph = (unsigned short*)sh_h;
        for (int i = tid; i < 2 * 2 * 16 * HS; i += 512) ph[i] = 0;
    }
    __syncthreads();

    const float2* xp = (const float2*)x + (size_t)(batch0 + n) * NT;
    float2 xv = xp[0];
    float c = 0.0f;
    float* outB = out + (size_t)batch0 * NT;

    int cur = 0;
    for (int t = 0; t < NT; ++t) {
        // C init = biases + W_ih * x_t (fp32)
        f32x4 acc;
#pragma unroll
        for (int r = 0; r < 4; ++r)
            acc[r] = fmaf(xv.x, wihx[r], fmaf(xv.y, wihy[r], bias[r]));

        // gates += W_hh * (h_hi + h_lo)
        const bf16x8 bhi = *(const bf16x8*)&sh_h[cur][0][n][8 * g];
        const bf16x8 blo = *(const bf16x8*)&sh_h[cur][1][n][8 * g];
        acc = __builtin_amdgcn_mfma_f32_16x16x32_bf16(afrag, bhi, acc, 0, 0, 0);
        acc = __builtin_amdgcn_mfma_f32_16x16x32_bf16(afrag, blo, acc, 0, 0, 0);

        const float2 xn = xp[(t + 1 < NT) ? t + 1 : t];   // prefetch

        // ---- activations (lane owns batch n, hidden j; c stays in reg) ----
        const float ig = fsig(acc[0]);
        const float fg = fsig(acc[1]);
        const float gg = ftanh(acc[2]);
        const float og = fsig(acc[3]);
        c = fmaf(fg, c, ig * gg);
        const float hk  = og * ftanh(c);
        const float thk = ftanh(hk);

        // ---- pack: pk0 = [bf16(hk) | bf16(thk)<<16]; hlo = residual ----
        const unsigned pk0 = cvt_pk_bf16(hk, thk);
        const float hlo = hk - __builtin_bit_cast(float, pk0 << 16);
        const unsigned pk1 = cvt_pk_bf16(hlo, hlo);

        const int nxt = cur ^ 1;
        const int tb  = (t >> 3) & 1;
        sh_h[nxt][0][n][j] = (unsigned short)pk0;          // h hi
        sh_h[nxt][1][n][j] = (unsigned short)pk1;          // h lo (residual)
        sh_t[tb][t & 7][n][j] = (unsigned short)(pk0 >> 16); // tanh(h)
        __syncthreads();   // the one barrier: h(t)/th(t) visible to all waves

        // ---- every 8 steps: wave wid computes head for time t-7+wid ----
        if ((t & 7) == 7) {
            const bf16x8 bth = *(const bf16x8*)&sh_t[tb][wid][n][8 * g];
            f32x4 hacc;
#pragma unroll
            for (int r = 0; r < 4; ++r) hacc[r] = b1r[r];
            hacc = __builtin_amdgcn_mfma_f32_16x16x32_bf16(w1hi, bth, hacc, 0, 0, 0);
            hacc = __builtin_amdgcn_mfma_f32_16x16x32_bf16(w1lo, bth, hacc, 0, 0, 0);
            float p = 0.0f;
#pragma unroll
            for (int r = 0; r < 4; ++r) p += ftanh(hacc[r]) * w2r[r];
            p += __shfl_xor(p, 16);    // fold the 4 row-groups g
            p += __shfl_xor(p, 32);
            if (g == 0)
                outB[(size_t)n * NT + (t - 7 + wid)] = p + b2v;
        }

        xv = xn;
        cur = nxt;
    }
}

extern "C" void kernel_launch(void* const* d_in, const int* in_sizes, int n_in,
                              void* d_out, int out_size, void* d_ws, size_t ws_size,
                              hipStream_t stream) {
    const float* x    = (const float*)d_in[0];
    const float* W_ih = (const float*)d_in[1];
    const float* W_hh = (const float*)d_in[2];
    const float* b_ih = (const float*)d_in[3];
    const float* b_hh = (const float*)d_in[4];
    const float* W1   = (const float*)d_in[5];
    const float* b1   = (const float*)d_in[6];
    const float* W2   = (const float*)d_in[7];
    const float* b2   = (const float*)d_in[8];
    float* out = (float*)d_out;

    lstm_mfma_kernel<<<dim3(NB / 16), dim3(512), 0, stream>>>(
        x, W_ih, W_hh, b_ih, b_hh, W1, b1, W2, b2, out);
}